// Round 6
// baseline (624.417 us; speedup 1.0000x reference)
//
#include <hip/hip_runtime.h>
#include <hip/hip_fp16.h>
#include <math.h>

#define RR 128          // spatial resolution (grid_space + features)
#define TT 150          // time resolution
#define NCH 48          // RANK*OUT_DIM*TIME_RANK
#define NF 32           // feature channels

typedef float vf2 __attribute__((ext_vector_type(2)));
typedef unsigned int u4v __attribute__((ext_vector_type(4)));

// unpack one uint (4 fp8 e4m3) and fma into a[0..3] with scale s
__device__ __forceinline__ void up4(uint u, float s, float* a) {
    vf2 lo = __builtin_amdgcn_cvt_pk_f32_fp8(u, false);
    vf2 hi = __builtin_amdgcn_cvt_pk_f32_fp8(u, true);
    a[0] = fmaf(s, lo[0], a[0]); a[1] = fmaf(s, lo[1], a[1]);
    a[2] = fmaf(s, hi[0], a[2]); a[3] = fmaf(s, hi[1], a[3]);
}
__device__ __forceinline__ void up16(u4v q, float s, float* a) {
    up4(q[0], s, a + 0); up4(q[1], s, a + 4);
    up4(q[2], s, a + 8); up4(q[3], s, a + 12);
}

// ---- transpose+cast grid_space [3][48][16384] f32 -> [3][16384][48] fp8 (x128) ----
__global__ __launch_bounds__(256) void tgsp_8(const float* __restrict__ in,
                                              uint* __restrict__ out) { // 4 fp8/word
    __shared__ float lds[48][65];
    const int t = threadIdx.x;
    const int p = blockIdx.x >> 8;          // plane
    const int tile = blockIdx.x & 255;
    const size_t V = (size_t)RR * RR;       // 16384
    const size_t v0 = (size_t)tile * 64;
    const float* ip = in + (size_t)p * NCH * V;
    uint* op = out + (size_t)p * V * 12;    // 12 words per position
    #pragma unroll
    for (int k = 0; k < 12; k++) {
        int idx = k * 256 + t; int c = idx >> 6; int vv = idx & 63;
        lds[c][vv] = ip[(size_t)c * V + v0 + vv];
    }
    __syncthreads();
    #pragma unroll
    for (int k = 0; k < 3; k++) {
        int idx = k * 256 + t; int vv = idx / 12; int cp = idx - vv * 12;
        float a = lds[4 * cp + 0][vv] * 128.f;
        float b = lds[4 * cp + 1][vv] * 128.f;
        float c = lds[4 * cp + 2][vv] * 128.f;
        float d = lds[4 * cp + 3][vv] * 128.f;
        uint w = (uint)__builtin_amdgcn_cvt_pk_fp8_f32(a, b, 0, false);
        w = (uint)__builtin_amdgcn_cvt_pk_fp8_f32(c, d, w, true);
        op[(v0 + vv) * 12 + cp] = w;
    }
}

// ---- main kernel: 2 rays per block (256 threads = 4 waves), 8 blocks/CU ----
// TR=true: gspace [3][R][R][48] fp8 x128; feat = ORIGINAL [32][R][R][R] f32
template<bool TR>
__global__ __launch_bounds__(256, 8) void lrv_main(
    const float* __restrict__ rays_d,
    const float* __restrict__ pts,
    const float* __restrict__ times,
    const float* __restrict__ deltas,
    const float* __restrict__ bg,
    const void* __restrict__ gspace_p,
    const float* __restrict__ gtime,    // [12][TT], L2-hot (7.2 KB)
    const float* __restrict__ feat,     // [NF][R][R][R] f32 (original)
    const float* __restrict__ W1, const float* __restrict__ b1,
    const float* __restrict__ W2, const float* __restrict__ b2,
    const float* __restrict__ Wc1, const float* __restrict__ bc1,
    const float* __restrict__ Wc2, const float* __restrict__ bc2,
    const int*  __restrict__ ridx,
    float* __restrict__ out)
{
    // LDS ~19.1 KB -> 8 blocks/CU
    __shared__ __align__(16) float4 sW1v[35 * 16];   // [i][j/4]
    __shared__ __align__(16) float4 sW2v[64 * 4];    // [j][k/4]
    __shared__ __align__(16) float4 sWc1v[18 * 16];  // [i][j/4]
    __shared__ __align__(16) float  sWc2[64 * 3];
    __shared__ float sb1[64], sbc1[64], sb2[16], sbc2[4];
    __shared__ float waveTot[4];
    __shared__ float4 rbuf[4];

    const int tid  = threadIdx.x;
    const int lane = tid & 63;
    const int wv   = tid >> 6;          // wave in block, 0..3

    {
        float* w1 = (float*)sW1v;
        for (int k = tid; k < 35 * 64; k += 256) w1[k] = W1[k];
        float* w2 = (float*)sW2v;
        for (int k = tid; k < 64 * 16; k += 256) w2[k] = W2[k];
        float* wc1 = (float*)sWc1v;
        for (int k = tid; k < 18 * 64; k += 256) wc1[k] = Wc1[k];
        for (int k = tid; k < 64 * 3; k += 256) sWc2[k] = Wc2[k];
        if (tid < 64) { sb1[tid] = b1[tid]; sbc1[tid] = bc1[tid]; }
        if (tid < 16) sb2[tid] = b2[tid];
        if (tid < 3)  sbc2[tid] = bc2[tid];
    }
    __syncthreads();

    const int ray = blockIdx.x * 2 + (tid >> 7);
    const int i   = ray * 128 + (tid & 127);

    // ---- 1D time grid sample -> itv[12] ----
    float itv[12];
    {
        float t = times[i];
        float x = (t + 1.f) * 0.5f * (float)(TT - 1);
        x = fminf(fmaxf(x, 0.f), (float)(TT - 1));
        int ti0 = (int)floorf(x);
        ti0 = min(max(ti0, 0), TT - 2);
        float tw = x - (float)ti0;
        #pragma unroll
        for (int c = 0; c < 12; c++) {
            float v0 = gtime[c * TT + ti0];
            float v1 = gtime[c * TT + ti0 + 1];
            itv[c] = fmaf(tw, v1 - v0, v0);
        }
    }

    // ---- 3 plane bilinear samples, low-rank contraction ----
    float p0 = pts[i * 3 + 0], p1 = pts[i * 3 + 1], p2 = pts[i * 3 + 2];
    int   pbia[3], pbib[3];
    float pw[3][4];
    {
        const float pa[3] = { p0, p0, p1 };
        const float pb[3] = { p1, p2, p2 };
        #pragma unroll
        for (int c = 0; c < 3; c++) {
            float xa = fminf(fmaxf((pa[c] + 1.f) * 0.5f * (float)(RR - 1), 0.f), (float)(RR - 1));
            float xb = fminf(fmaxf((pb[c] + 1.f) * 0.5f * (float)(RR - 1), 0.f), (float)(RR - 1));
            int ia = min(max((int)floorf(xa), 0), RR - 2);
            int ib = min(max((int)floorf(xb), 0), RR - 2);
            float wa = xa - (float)ia, wb = xb - (float)ib;
            pbia[c] = ia; pbib[c] = ib;
            pw[c][0] = (1.f - wa) * (1.f - wb);
            pw[c][1] = (1.f - wa) * wb;
            pw[c][2] = wa * (1.f - wb);
            pw[c][3] = wa * wb;
        }
    }
    float S12[12];
    if constexpr (TR) {
        // gspace: [3][RR][RR][48] fp8 (x128), 12 words/position
        const uint* gs = (const uint*)gspace_p;
        uint b[3][4];
        #pragma unroll
        for (int c = 0; c < 3; c++) {
            uint b00 = ((uint)c * (RR * RR) + (uint)pbia[c] * RR + (uint)pbib[c]) * 12u;
            b[c][0] = b00;           b[c][1] = b00 + 12u;
            b[c][2] = b00 + RR * 12u; b[c][3] = b00 + RR * 12u + 12u;
        }
        #pragma unroll
        for (int cb = 0; cb < 3; cb++) {       // 16 channels per iteration
            float pr[16];
            #pragma unroll
            for (int p = 0; p < 3; p++) {
                float a[16];
                #pragma unroll
                for (int j = 0; j < 16; j++) a[j] = 0.f;
                #pragma unroll
                for (int corner = 0; corner < 4; corner++) {
                    u4v q = *reinterpret_cast<const u4v*>(gs + b[p][corner] + cb * 4);
                    up16(q, pw[p][corner] * 0.0078125f, a);   // 1/128
                }
                #pragma unroll
                for (int j = 0; j < 16; j++) pr[j] = (p == 0) ? a[j] : pr[j] * a[j];
            }
            #pragma unroll
            for (int g = 0; g < 4; g++)
                S12[cb * 4 + g] = pr[g * 4 + 0] + pr[g * 4 + 1]
                                + pr[g * 4 + 2] + pr[g * 4 + 3];
        }
    } else {
        const float* gs = (const float*)gspace_p;
        #pragma unroll
        for (int k = 0; k < 12; k++) S12[k] = 0.f;
        #pragma unroll 4
        for (int ch = 0; ch < NCH; ch++) {
            float prod = 1.f;
            #pragma unroll
            for (int c = 0; c < 3; c++) {
                const float* g = gs + (size_t)(c * NCH + ch) * (RR * RR)
                               + pbia[c] * RR + pbib[c];
                float v = pw[c][0] * g[0] + pw[c][1] * g[1]
                        + pw[c][2] * g[RR] + pw[c][3] * g[RR + 1];
                prod *= v;
            }
            S12[ch >> 2] += prod;
        }
    }
    float cc[3];
    #pragma unroll
    for (int o = 0; o < 3; o++) {
        float a = 0.f;
        #pragma unroll
        for (int t = 0; t < 4; t++) a += S12[o * 4 + t] * itv[o * 4 + t];
        cc[o] = fminf(fmaxf(a, -1.f), 1.f);
    }

    // ---- 3D feature trilinear sample (original layout; hot-cached region) ----
    float in35[36];
    {
        int   fi[3];
        float fw[3];
        #pragma unroll
        for (int k = 0; k < 3; k++) {
            float xk = fminf(fmaxf((cc[k] + 1.f) * 0.5f * (float)(RR - 1), 0.f), (float)(RR - 1));
            int ik = min(max((int)floorf(xk), 0), RR - 2);
            fi[k] = ik; fw[k] = xk - (float)ik;
        }
        float w0 = fw[0], w1 = fw[1], w2 = fw[2];
        float cw0 = (1.f - w0) * (1.f - w1) * (1.f - w2);
        float cw1 = (1.f - w0) * (1.f - w1) * w2;
        float cw2 = (1.f - w0) * w1 * (1.f - w2);
        float cw3 = (1.f - w0) * w1 * w2;
        float cw4 = w0 * (1.f - w1) * (1.f - w2);
        float cw5 = w0 * (1.f - w1) * w2;
        float cw6 = w0 * w1 * (1.f - w2);
        float cw7 = w0 * w1 * w2;
        size_t fb = ((size_t)fi[0] * RR + fi[1]) * RR + fi[2];
        #pragma unroll 4
        for (int ch = 0; ch < NF; ch++) {
            const float* f = feat + (size_t)ch * (RR * RR * RR) + fb;
            in35[ch] = cw0 * f[0]            + cw1 * f[1]
                     + cw2 * f[RR]           + cw3 * f[RR + 1]
                     + cw4 * f[RR * RR]      + cw5 * f[RR * RR + 1]
                     + cw6 * f[RR * RR + RR] + cw7 * f[RR * RR + RR + 1];
        }
    }
    // ray direction (normalized)
    {
        int r = ridx[i];
        float d0 = rays_d[r * 3 + 0], d1 = rays_d[r * 3 + 1], d2 = rays_d[r * 3 + 2];
        float inv = 1.f / sqrtf(d0 * d0 + d1 * d1 + d2 * d2);
        in35[32] = d0 * inv; in35[33] = d1 * inv; in35[34] = d2 * inv;
    }

    // ---- MLP: (35 -> 64 relu -> 16), fused ----
    float sacc[16];
    #pragma unroll
    for (int k = 0; k < 16; k++) sacc[k] = sb2[k];
    #pragma unroll 2
    for (int jb = 0; jb < 16; jb++) {
        float a0 = sb1[jb * 4 + 0], a1 = sb1[jb * 4 + 1];
        float a2 = sb1[jb * 4 + 2], a3 = sb1[jb * 4 + 3];
        #pragma unroll
        for (int ii = 0; ii < 35; ii++) {
            float xv = in35[ii];
            float4 wvv = sW1v[ii * 16 + jb];
            a0 = fmaf(xv, wvv.x, a0); a1 = fmaf(xv, wvv.y, a1);
            a2 = fmaf(xv, wvv.z, a2); a3 = fmaf(xv, wvv.w, a3);
        }
        a0 = fmaxf(a0, 0.f); a1 = fmaxf(a1, 0.f);
        a2 = fmaxf(a2, 0.f); a3 = fmaxf(a3, 0.f);
        #pragma unroll
        for (int kg = 0; kg < 4; kg++) {
            float4 r0 = sW2v[(jb * 4 + 0) * 4 + kg];
            float4 r1 = sW2v[(jb * 4 + 1) * 4 + kg];
            float4 r2 = sW2v[(jb * 4 + 2) * 4 + kg];
            float4 r3 = sW2v[(jb * 4 + 3) * 4 + kg];
            sacc[kg * 4 + 0] += a0 * r0.x + a1 * r1.x + a2 * r2.x + a3 * r3.x;
            sacc[kg * 4 + 1] += a0 * r0.y + a1 * r1.y + a2 * r2.y + a3 * r3.y;
            sacc[kg * 4 + 2] += a0 * r0.z + a1 * r1.z + a2 * r2.z + a3 * r3.z;
            sacc[kg * 4 + 3] += a0 * r0.w + a1 * r1.w + a2 * r2.w + a3 * r3.w;
        }
    }
    float sigma = expf(fminf(fmaxf(sacc[0], -15.f), 15.f));

    // ---- color MLP: (15+3 -> 64 relu -> 3), fused ----
    float in18[18];
    #pragma unroll
    for (int k = 0; k < 15; k++) in18[k] = sacc[k + 1];
    in18[15] = in35[32]; in18[16] = in35[33]; in18[17] = in35[34];
    float rc0 = sbc2[0], rc1 = sbc2[1], rc2 = sbc2[2];
    #pragma unroll 2
    for (int jb = 0; jb < 16; jb++) {
        float a0 = sbc1[jb * 4 + 0], a1 = sbc1[jb * 4 + 1];
        float a2 = sbc1[jb * 4 + 2], a3 = sbc1[jb * 4 + 3];
        #pragma unroll
        for (int ii = 0; ii < 18; ii++) {
            float xv = in18[ii];
            float4 wvv = sWc1v[ii * 16 + jb];
            a0 = fmaf(xv, wvv.x, a0); a1 = fmaf(xv, wvv.y, a1);
            a2 = fmaf(xv, wvv.z, a2); a3 = fmaf(xv, wvv.w, a3);
        }
        a0 = fmaxf(a0, 0.f); a1 = fmaxf(a1, 0.f);
        a2 = fmaxf(a2, 0.f); a3 = fmaxf(a3, 0.f);
        rc0 += a0 * sWc2[(jb * 4 + 0) * 3 + 0] + a1 * sWc2[(jb * 4 + 1) * 3 + 0]
             + a2 * sWc2[(jb * 4 + 2) * 3 + 0] + a3 * sWc2[(jb * 4 + 3) * 3 + 0];
        rc1 += a0 * sWc2[(jb * 4 + 0) * 3 + 1] + a1 * sWc2[(jb * 4 + 1) * 3 + 1]
             + a2 * sWc2[(jb * 4 + 2) * 3 + 1] + a3 * sWc2[(jb * 4 + 3) * 3 + 1];
        rc2 += a0 * sWc2[(jb * 4 + 0) * 3 + 2] + a1 * sWc2[(jb * 4 + 1) * 3 + 2]
             + a2 * sWc2[(jb * 4 + 2) * 3 + 2] + a3 * sWc2[(jb * 4 + 3) * 3 + 2];
    }
    float r_ = 1.f / (1.f + expf(-rc0));
    float g_ = 1.f / (1.f + expf(-rc1));
    float b_ = 1.f / (1.f + expf(-rc2));

    // ---- per-ray compositing: exclusive scan of tau over 128 samples ----
    float tau = sigma * deltas[i];
    float v = tau;
    #pragma unroll
    for (int off = 1; off < 64; off <<= 1) {
        float u = __shfl_up(v, off, 64);
        if (lane >= off) v += u;
    }
    if (lane == 63) waveTot[wv] = v;
    float excl = v - tau;
    __syncthreads();
    if (wv & 1) excl += waveTot[wv & 2];

    float Tr = expf(-excl);
    float w  = Tr * (1.f - expf(-tau));

    float ax = w * r_, ay = w * g_, az = w * b_, aw = w;
    #pragma unroll
    for (int off = 32; off; off >>= 1) {
        ax += __shfl_down(ax, off, 64);
        ay += __shfl_down(ay, off, 64);
        az += __shfl_down(az, off, 64);
        aw += __shfl_down(aw, off, 64);
    }
    if (lane == 0) rbuf[wv] = make_float4(ax, ay, az, aw);
    __syncthreads();
    if (lane == 0 && (wv & 1) == 0) {
        float cx = rbuf[wv].x + rbuf[wv + 1].x;
        float cy = rbuf[wv].y + rbuf[wv + 1].y;
        float cz = rbuf[wv].z + rbuf[wv + 1].z;
        float alpha = rbuf[wv].w + rbuf[wv + 1].w;
        out[ray * 3 + 0] = cx + (1.f - alpha) * bg[ray * 3 + 0];
        out[ray * 3 + 1] = cy + (1.f - alpha) * bg[ray * 3 + 1];
        out[ray * 3 + 2] = cz + (1.f - alpha) * bg[ray * 3 + 2];
    }
}

extern "C" void kernel_launch(void* const* d_in, const int* in_sizes, int n_in,
                              void* d_out, int out_size, void* d_ws, size_t ws_size,
                              hipStream_t stream) {
    const float* rays_d = (const float*)d_in[0];
    const float* pts    = (const float*)d_in[1];
    const float* times  = (const float*)d_in[2];
    const float* deltas = (const float*)d_in[3];
    const float* bg     = (const float*)d_in[4];
    const float* gspace = (const float*)d_in[5];
    const float* gtime  = (const float*)d_in[6];
    const float* feat   = (const float*)d_in[7];
    const float* W1  = (const float*)d_in[8];
    const float* b1  = (const float*)d_in[9];
    const float* W2  = (const float*)d_in[10];
    const float* b2  = (const float*)d_in[11];
    const float* Wc1 = (const float*)d_in[12];
    const float* bc1 = (const float*)d_in[13];
    const float* Wc2 = (const float*)d_in[14];
    const float* bc2 = (const float*)d_in[15];
    const int*   ridx = (const int*)d_in[16];

    const int n_rays = in_sizes[0] / 3;   // 4096

    const size_t GSP_8B = (size_t)3 * RR * RR * NCH;   // 2.35 MB (fp8)

    if (ws_size >= GSP_8B) {
        uint* gsp_t = (uint*)d_ws;
        tgsp_8<<<dim3(3 * 256), dim3(256), 0, stream>>>(gspace, gsp_t);
        lrv_main<true><<<dim3(n_rays / 2), dim3(256), 0, stream>>>(
            rays_d, pts, times, deltas, bg, (const void*)gsp_t, gtime, feat,
            W1, b1, W2, b2, Wc1, bc1, Wc2, bc2, ridx, (float*)d_out);
    } else {
        lrv_main<false><<<dim3(n_rays / 2), dim3(256), 0, stream>>>(
            rays_d, pts, times, deltas, bg, (const void*)gspace, gtime, feat,
            W1, b1, W2, b2, Wc1, bc1, Wc2, bc2, ridx, (float*)d_out);
    }
}

// Round 7
// 202.887 us; speedup vs baseline: 3.0777x; 3.0777x over previous
//
#include <hip/hip_runtime.h>
#include <hip/hip_fp16.h>
#include <math.h>

#define RR 128          // spatial resolution (grid_space + features)
#define TT 150          // time resolution
#define NCH 48          // RANK*OUT_DIM*TIME_RANK
#define NF 32           // feature channels

typedef float vf2 __attribute__((ext_vector_type(2)));
typedef unsigned int u4v __attribute__((ext_vector_type(4)));

// unpack one uint (4 fp8 e4m3) and fma into a[0..3] with scale s
__device__ __forceinline__ void up4(uint u, float s, float* a) {
    vf2 lo = __builtin_amdgcn_cvt_pk_f32_fp8(u, false);
    vf2 hi = __builtin_amdgcn_cvt_pk_f32_fp8(u, true);
    a[0] = fmaf(s, lo[0], a[0]); a[1] = fmaf(s, lo[1], a[1]);
    a[2] = fmaf(s, hi[0], a[2]); a[3] = fmaf(s, hi[1], a[3]);
}
__device__ __forceinline__ void up16(u4v q, float s, float* a) {
    up4(q[0], s, a + 0); up4(q[1], s, a + 4);
    up4(q[2], s, a + 8); up4(q[3], s, a + 12);
}

// ---- transpose+cast grid_space [3][48][16384] f32 -> [3][16384][48] fp8 (x128) ----
__global__ __launch_bounds__(256) void tgsp_8(const float* __restrict__ in,
                                              uint* __restrict__ out) { // 4 fp8/word
    __shared__ float lds[48][65];
    const int t = threadIdx.x;
    const int p = blockIdx.x >> 8;          // plane
    const int tile = blockIdx.x & 255;
    const size_t V = (size_t)RR * RR;       // 16384
    const size_t v0 = (size_t)tile * 64;
    const float* ip = in + (size_t)p * NCH * V;
    uint* op = out + (size_t)p * V * 12;    // 12 words per position
    #pragma unroll
    for (int k = 0; k < 12; k++) {
        int idx = k * 256 + t; int c = idx >> 6; int vv = idx & 63;
        lds[c][vv] = ip[(size_t)c * V + v0 + vv];
    }
    __syncthreads();
    #pragma unroll
    for (int k = 0; k < 3; k++) {
        int idx = k * 256 + t; int vv = idx / 12; int cp = idx - vv * 12;
        float a = lds[4 * cp + 0][vv] * 128.f;
        float b = lds[4 * cp + 1][vv] * 128.f;
        float c = lds[4 * cp + 2][vv] * 128.f;
        float d = lds[4 * cp + 3][vv] * 128.f;
        uint w = (uint)__builtin_amdgcn_cvt_pk_fp8_f32(a, b, 0, false);
        w = (uint)__builtin_amdgcn_cvt_pk_fp8_f32(c, d, w, true);
        op[(v0 + vv) * 12 + cp] = w;
    }
}

// ---- main kernel: 2 rays per block (256 threads = 4 waves) ----
// TR=true: gspace [3][R][R][48] fp8 x128. feat ALWAYS original [32][R][R][R] f32.
template<bool TR>
__global__ __launch_bounds__(256, 5) void lrv_main(
    const float* __restrict__ rays_d,
    const float* __restrict__ pts,
    const float* __restrict__ times,
    const float* __restrict__ deltas,
    const float* __restrict__ bg,
    const void* __restrict__ gspace_p,
    const float* __restrict__ gtime,    // [12][TT]
    const float* __restrict__ feat,     // [NF][R][R][R] f32 (original)
    const float* __restrict__ W1, const float* __restrict__ b1,
    const float* __restrict__ W2, const float* __restrict__ b2,
    const float* __restrict__ Wc1, const float* __restrict__ bc1,
    const float* __restrict__ Wc2, const float* __restrict__ bc2,
    const int*  __restrict__ ridx,
    float* __restrict__ out)
{
    __shared__ __align__(16) float4 sW1v[35 * 16];   // [i][j/4]
    __shared__ __align__(16) float4 sW2v[64 * 4];    // [j][k/4]
    __shared__ __align__(16) float4 sWc1v[18 * 16];  // [i][j/4]
    __shared__ __align__(16) float  sWc2[64 * 3];
    __shared__ float sb1[64], sbc1[64], sb2[16], sbc2[4];
    __shared__ float sGT[12 * TT];
    __shared__ __align__(16) float4 sFeatV[8][8];    // 8 corners x 32 ch
    __shared__ int sV[4], sU[4];
    __shared__ float waveTot[4];
    __shared__ float4 rbuf[4];

    const int tid  = threadIdx.x;
    const int lane = tid & 63;
    const int wv   = tid >> 6;          // wave in block, 0..3

    {
        float* w1 = (float*)sW1v;
        for (int k = tid; k < 35 * 64; k += 256) w1[k] = W1[k];
        float* w2 = (float*)sW2v;
        for (int k = tid; k < 64 * 16; k += 256) w2[k] = W2[k];
        float* wc1 = (float*)sWc1v;
        for (int k = tid; k < 18 * 64; k += 256) wc1[k] = Wc1[k];
        for (int k = tid; k < 64 * 3; k += 256) sWc2[k] = Wc2[k];
        if (tid < 64) { sb1[tid] = b1[tid]; sbc1[tid] = bc1[tid]; }
        if (tid < 16) sb2[tid] = b2[tid];
        if (tid < 3)  sbc2[tid] = bc2[tid];
        for (int k = tid; k < 12 * TT; k += 256) sGT[k] = gtime[k];
    }
    __syncthreads();

    const int ray = blockIdx.x * 2 + (tid >> 7);
    const int i   = ray * 128 + (tid & 127);

    // ---- 1D time grid sample -> itv[12] ----
    float itv[12];
    {
        float t = times[i];
        float x = (t + 1.f) * 0.5f * (float)(TT - 1);
        x = fminf(fmaxf(x, 0.f), (float)(TT - 1));
        int ti0 = (int)floorf(x);
        ti0 = min(max(ti0, 0), TT - 2);
        float tw = x - (float)ti0;
        #pragma unroll
        for (int c = 0; c < 12; c++) {
            float v0 = sGT[c * TT + ti0];
            float v1 = sGT[c * TT + ti0 + 1];
            itv[c] = fmaf(tw, v1 - v0, v0);
        }
    }

    // ---- 3 plane bilinear samples, low-rank contraction ----
    float p0 = pts[i * 3 + 0], p1 = pts[i * 3 + 1], p2 = pts[i * 3 + 2];
    int   pbia[3], pbib[3];
    float pw[3][4];
    {
        const float pa[3] = { p0, p0, p1 };
        const float pb[3] = { p1, p2, p2 };
        #pragma unroll
        for (int c = 0; c < 3; c++) {
            float xa = fminf(fmaxf((pa[c] + 1.f) * 0.5f * (float)(RR - 1), 0.f), (float)(RR - 1));
            float xb = fminf(fmaxf((pb[c] + 1.f) * 0.5f * (float)(RR - 1), 0.f), (float)(RR - 1));
            int ia = min(max((int)floorf(xa), 0), RR - 2);
            int ib = min(max((int)floorf(xb), 0), RR - 2);
            float wa = xa - (float)ia, wb = xb - (float)ib;
            pbia[c] = ia; pbib[c] = ib;
            pw[c][0] = (1.f - wa) * (1.f - wb);
            pw[c][1] = (1.f - wa) * wb;
            pw[c][2] = wa * (1.f - wb);
            pw[c][3] = wa * wb;
        }
    }
    float S12[12];
    if constexpr (TR) {
        // gspace: [3][RR][RR][48] fp8 (x128), 12 words/position (48B, 16B-aligned)
        const uint* gs = (const uint*)gspace_p;
        uint b[3][4];
        #pragma unroll
        for (int c = 0; c < 3; c++) {
            uint b00 = ((uint)c * (RR * RR) + (uint)pbia[c] * RR + (uint)pbib[c]) * 12u;
            b[c][0] = b00;            b[c][1] = b00 + 12u;
            b[c][2] = b00 + RR * 12u; b[c][3] = b00 + RR * 12u + 12u;
        }
        #pragma unroll
        for (int cb = 0; cb < 3; cb++) {       // 16 channels per iteration
            float pr[16];
            #pragma unroll
            for (int p = 0; p < 3; p++) {
                float a[16];
                #pragma unroll
                for (int j = 0; j < 16; j++) a[j] = 0.f;
                #pragma unroll
                for (int corner = 0; corner < 4; corner++) {
                    u4v q = *reinterpret_cast<const u4v*>(gs + b[p][corner] + cb * 4);
                    up16(q, pw[p][corner] * 0.0078125f, a);   // 1/128
                }
                #pragma unroll
                for (int j = 0; j < 16; j++) pr[j] = (p == 0) ? a[j] : pr[j] * a[j];
            }
            #pragma unroll
            for (int g = 0; g < 4; g++)
                S12[cb * 4 + g] = pr[g * 4 + 0] + pr[g * 4 + 1]
                                + pr[g * 4 + 2] + pr[g * 4 + 3];
        }
    } else {
        const float* gs = (const float*)gspace_p;
        #pragma unroll
        for (int k = 0; k < 12; k++) S12[k] = 0.f;
        #pragma unroll 4
        for (int ch = 0; ch < NCH; ch++) {
            float prod = 1.f;
            #pragma unroll
            for (int c = 0; c < 3; c++) {
                const float* g = gs + (size_t)(c * NCH + ch) * (RR * RR)
                               + pbia[c] * RR + pbib[c];
                float v = pw[c][0] * g[0] + pw[c][1] * g[1]
                        + pw[c][2] * g[RR] + pw[c][3] * g[RR + 1];
                prod *= v;
            }
            S12[ch >> 2] += prod;
        }
    }
    float cc[3];
    #pragma unroll
    for (int o = 0; o < 3; o++) {
        float a = 0.f;
        #pragma unroll
        for (int t = 0; t < 4; t++) a += S12[o * 4 + t] * itv[o * 4 + t];
        cc[o] = fminf(fmaxf(a, -1.f), 1.f);
    }

    // ---- 3D feature trilinear sample ----
    __align__(16) float in35[36];
    int   fi[3];
    float cw[8];
    {
        float fw[3];
        #pragma unroll
        for (int k = 0; k < 3; k++) {
            float xk = fminf(fmaxf((cc[k] + 1.f) * 0.5f * (float)(RR - 1), 0.f), (float)(RR - 1));
            int ik = min(max((int)floorf(xk), 0), RR - 2);
            fi[k] = ik; fw[k] = xk - (float)ik;
        }
        float w0 = fw[0], w1 = fw[1], w2 = fw[2];
        cw[0] = (1.f - w0) * (1.f - w1) * (1.f - w2);
        cw[1] = (1.f - w0) * (1.f - w1) * w2;
        cw[2] = (1.f - w0) * w1 * (1.f - w2);
        cw[3] = (1.f - w0) * w1 * w2;
        cw[4] = w0 * (1.f - w1) * (1.f - w2);
        cw[5] = w0 * (1.f - w1) * w2;
        cw[6] = w0 * w1 * (1.f - w2);
        cw[7] = w0 * w1 * w2;
    }
    // block-wide vote: do all 256 samples share one base voxel?
    {
        int packed = (fi[0] << 16) | (fi[1] << 8) | fi[2];
        int first  = __builtin_amdgcn_readfirstlane(packed);
        unsigned long long bal = __ballot(packed == first);
        if (lane == 0) { sV[wv] = first; sU[wv] = (bal == ~0ull) ? 1 : 0; }
    }
    __syncthreads();
    const bool uni = sU[0] && sU[1] && sU[2] && sU[3] &&
                     sV[0] == sV[1] && sV[1] == sV[2] && sV[2] == sV[3];
    const size_t V3 = (size_t)RR * RR * RR;
    if (uni) {
        // cooperative load: 8 corners x 32 channels -> LDS (1 KB), then broadcast-interp
        {
            int c  = tid >> 5;           // corner 0..7  (bit2=x, bit1=y, bit0=z)
            int ch = tid & 31;
            size_t off = (((size_t)(fi[0] + ((c >> 2) & 1)) * RR
                         + (size_t)(fi[1] + ((c >> 1) & 1))) * RR
                         + (size_t)(fi[2] + (c & 1)));
            ((float*)sFeatV)[c * 32 + ch] = feat[(size_t)ch * V3 + off];
        }
        __syncthreads();
        float4* in4 = reinterpret_cast<float4*>(in35);
        #pragma unroll
        for (int chq = 0; chq < 8; chq++) {
            float4 acc = make_float4(0.f, 0.f, 0.f, 0.f);
            #pragma unroll
            for (int c = 0; c < 8; c++) {
                float4 v = sFeatV[c][chq];
                acc.x = fmaf(cw[c], v.x, acc.x);
                acc.y = fmaf(cw[c], v.y, acc.y);
                acc.z = fmaf(cw[c], v.z, acc.z);
                acc.w = fmaf(cw[c], v.w, acc.w);
            }
            in4[chq] = acc;
        }
    } else {
        // general fallback: per-thread gather from original layout
        size_t fb = ((size_t)fi[0] * RR + fi[1]) * RR + fi[2];
        #pragma unroll 4
        for (int ch = 0; ch < NF; ch++) {
            const float* f = feat + (size_t)ch * V3 + fb;
            in35[ch] = cw[0] * f[0]            + cw[1] * f[1]
                     + cw[2] * f[RR]           + cw[3] * f[RR + 1]
                     + cw[4] * f[RR * RR]      + cw[5] * f[RR * RR + 1]
                     + cw[6] * f[RR * RR + RR] + cw[7] * f[RR * RR + RR + 1];
        }
    }
    // ray direction (normalized)
    {
        int r = ridx[i];
        float d0 = rays_d[r * 3 + 0], d1 = rays_d[r * 3 + 1], d2 = rays_d[r * 3 + 2];
        float inv = 1.f / sqrtf(d0 * d0 + d1 * d1 + d2 * d2);
        in35[32] = d0 * inv; in35[33] = d1 * inv; in35[34] = d2 * inv;
    }

    // ---- MLP: (35 -> 64 relu -> 16), fused ----
    float sacc[16];
    #pragma unroll
    for (int k = 0; k < 16; k++) sacc[k] = sb2[k];
    #pragma unroll 2
    for (int jb = 0; jb < 16; jb++) {
        float a0 = sb1[jb * 4 + 0], a1 = sb1[jb * 4 + 1];
        float a2 = sb1[jb * 4 + 2], a3 = sb1[jb * 4 + 3];
        #pragma unroll
        for (int ii = 0; ii < 35; ii++) {
            float xv = in35[ii];
            float4 wvv = sW1v[ii * 16 + jb];
            a0 = fmaf(xv, wvv.x, a0); a1 = fmaf(xv, wvv.y, a1);
            a2 = fmaf(xv, wvv.z, a2); a3 = fmaf(xv, wvv.w, a3);
        }
        a0 = fmaxf(a0, 0.f); a1 = fmaxf(a1, 0.f);
        a2 = fmaxf(a2, 0.f); a3 = fmaxf(a3, 0.f);
        #pragma unroll
        for (int kg = 0; kg < 4; kg++) {
            float4 r0 = sW2v[(jb * 4 + 0) * 4 + kg];
            float4 r1 = sW2v[(jb * 4 + 1) * 4 + kg];
            float4 r2 = sW2v[(jb * 4 + 2) * 4 + kg];
            float4 r3 = sW2v[(jb * 4 + 3) * 4 + kg];
            sacc[kg * 4 + 0] += a0 * r0.x + a1 * r1.x + a2 * r2.x + a3 * r3.x;
            sacc[kg * 4 + 1] += a0 * r0.y + a1 * r1.y + a2 * r2.y + a3 * r3.y;
            sacc[kg * 4 + 2] += a0 * r0.z + a1 * r1.z + a2 * r2.z + a3 * r3.z;
            sacc[kg * 4 + 3] += a0 * r0.w + a1 * r1.w + a2 * r2.w + a3 * r3.w;
        }
    }
    float sigma = expf(fminf(fmaxf(sacc[0], -15.f), 15.f));

    // ---- color MLP: (15+3 -> 64 relu -> 3), fused ----
    float in18[18];
    #pragma unroll
    for (int k = 0; k < 15; k++) in18[k] = sacc[k + 1];
    in18[15] = in35[32]; in18[16] = in35[33]; in18[17] = in35[34];
    float rc0 = sbc2[0], rc1 = sbc2[1], rc2 = sbc2[2];
    #pragma unroll 2
    for (int jb = 0; jb < 16; jb++) {
        float a0 = sbc1[jb * 4 + 0], a1 = sbc1[jb * 4 + 1];
        float a2 = sbc1[jb * 4 + 2], a3 = sbc1[jb * 4 + 3];
        #pragma unroll
        for (int ii = 0; ii < 18; ii++) {
            float xv = in18[ii];
            float4 wvv = sWc1v[ii * 16 + jb];
            a0 = fmaf(xv, wvv.x, a0); a1 = fmaf(xv, wvv.y, a1);
            a2 = fmaf(xv, wvv.z, a2); a3 = fmaf(xv, wvv.w, a3);
        }
        a0 = fmaxf(a0, 0.f); a1 = fmaxf(a1, 0.f);
        a2 = fmaxf(a2, 0.f); a3 = fmaxf(a3, 0.f);
        rc0 += a0 * sWc2[(jb * 4 + 0) * 3 + 0] + a1 * sWc2[(jb * 4 + 1) * 3 + 0]
             + a2 * sWc2[(jb * 4 + 2) * 3 + 0] + a3 * sWc2[(jb * 4 + 3) * 3 + 0];
        rc1 += a0 * sWc2[(jb * 4 + 0) * 3 + 1] + a1 * sWc2[(jb * 4 + 1) * 3 + 1]
             + a2 * sWc2[(jb * 4 + 2) * 3 + 1] + a3 * sWc2[(jb * 4 + 3) * 3 + 1];
        rc2 += a0 * sWc2[(jb * 4 + 0) * 3 + 2] + a1 * sWc2[(jb * 4 + 1) * 3 + 2]
             + a2 * sWc2[(jb * 4 + 2) * 3 + 2] + a3 * sWc2[(jb * 4 + 3) * 3 + 2];
    }
    float r_ = 1.f / (1.f + expf(-rc0));
    float g_ = 1.f / (1.f + expf(-rc1));
    float b_ = 1.f / (1.f + expf(-rc2));

    // ---- per-ray compositing: exclusive scan of tau over 128 samples ----
    float tau = sigma * deltas[i];
    float v = tau;
    #pragma unroll
    for (int off = 1; off < 64; off <<= 1) {
        float u = __shfl_up(v, off, 64);
        if (lane >= off) v += u;
    }
    if (lane == 63) waveTot[wv] = v;
    float excl = v - tau;
    __syncthreads();
    if (wv & 1) excl += waveTot[wv & 2];

    float Tr = expf(-excl);
    float w  = Tr * (1.f - expf(-tau));

    float ax = w * r_, ay = w * g_, az = w * b_, aw = w;
    #pragma unroll
    for (int off = 32; off; off >>= 1) {
        ax += __shfl_down(ax, off, 64);
        ay += __shfl_down(ay, off, 64);
        az += __shfl_down(az, off, 64);
        aw += __shfl_down(aw, off, 64);
    }
    if (lane == 0) rbuf[wv] = make_float4(ax, ay, az, aw);
    __syncthreads();
    if (lane == 0 && (wv & 1) == 0) {
        float cx = rbuf[wv].x + rbuf[wv + 1].x;
        float cy = rbuf[wv].y + rbuf[wv + 1].y;
        float cz = rbuf[wv].z + rbuf[wv + 1].z;
        float alpha = rbuf[wv].w + rbuf[wv + 1].w;
        out[ray * 3 + 0] = cx + (1.f - alpha) * bg[ray * 3 + 0];
        out[ray * 3 + 1] = cy + (1.f - alpha) * bg[ray * 3 + 1];
        out[ray * 3 + 2] = cz + (1.f - alpha) * bg[ray * 3 + 2];
    }
}

extern "C" void kernel_launch(void* const* d_in, const int* in_sizes, int n_in,
                              void* d_out, int out_size, void* d_ws, size_t ws_size,
                              hipStream_t stream) {
    const float* rays_d = (const float*)d_in[0];
    const float* pts    = (const float*)d_in[1];
    const float* times  = (const float*)d_in[2];
    const float* deltas = (const float*)d_in[3];
    const float* bg     = (const float*)d_in[4];
    const float* gspace = (const float*)d_in[5];
    const float* gtime  = (const float*)d_in[6];
    const float* feat   = (const float*)d_in[7];
    const float* W1  = (const float*)d_in[8];
    const float* b1  = (const float*)d_in[9];
    const float* W2  = (const float*)d_in[10];
    const float* b2  = (const float*)d_in[11];
    const float* Wc1 = (const float*)d_in[12];
    const float* bc1 = (const float*)d_in[13];
    const float* Wc2 = (const float*)d_in[14];
    const float* bc2 = (const float*)d_in[15];
    const int*   ridx = (const int*)d_in[16];

    const int n_rays = in_sizes[0] / 3;   // 4096

    const size_t GSP_8B = (size_t)3 * RR * RR * NCH;   // 2.35 MB (fp8)

    if (ws_size >= GSP_8B) {
        uint* gsp_t = (uint*)d_ws;
        tgsp_8<<<dim3(3 * 256), dim3(256), 0, stream>>>(gspace, gsp_t);
        lrv_main<true><<<dim3(n_rays / 2), dim3(256), 0, stream>>>(
            rays_d, pts, times, deltas, bg, (const void*)gsp_t, gtime, feat,
            W1, b1, W2, b2, Wc1, bc1, Wc2, bc2, ridx, (float*)d_out);
    } else {
        lrv_main<false><<<dim3(n_rays / 2), dim3(256), 0, stream>>>(
            rays_d, pts, times, deltas, bg, (const void*)gspace, gtime, feat,
            W1, b1, W2, b2, Wc1, bc1, Wc2, bc2, ridx, (float*)d_out);
    }
}